// Round 4
// baseline (117.413 us; speedup 1.0000x reference)
//
#include <hip/hip_runtime.h>
#include <hip/hip_bf16.h>

// Problem constants
#define BB 8
#define HH 640
#define WW 640
#define HWN (HH * WW)          // 409600 pixels per batch
#define NUM_INST 16
#define NBLK 200               // blocks per batch; 200*256*2 float4 == 102400 == HWN/4 exactly
#define NBLK_TOT (NBLK * BB)   // 1600 blocks total
#define THREADS 256
#define NV 36                  // 16 s12 | 16 cnt | pos, all, or, posCnt
#define HALF_VEC (NBLK * THREADS)  // 51200 float4s per batch half

// ws layout: ws[v * NBLK_TOT + g], g = b*NBLK + blockIdx.x. 36*1600*4 = 230400 B.

__device__ __forceinline__ void process_pixel(
    float p1, float p2, float c, float t, int k,
    float* s12, unsigned* cnt_s,
    float& accPos, float& accAll, float& accOr, unsigned& posCnt)
{
    float andp = p1 * p2;
    bool tpos = (t != 0.0f);
    bool cpos = (c != 0.0f);
    // BCE(and_preds, overlap): overlap exactly 0/1 -> one log, select argument
    float argA = tpos ? andp : (1.0f - andp);
    float bce = -fmaxf(__logf(argA), -100.0f);
    accAll += bce;
    accPos += cpos ? bce : 0.0f;
    posCnt += (unsigned)__popcll(__ballot(cpos));   // scalar-pipe count
    // BCE(max(p1,p2), conf)
    float mx = fmaxf(p1, p2);
    float argO = cpos ? mx : (1.0f - mx);
    accOr -= fmaxf(__logf(argO), -100.0f);
    // instance term: |d1-d2| = |s1-s2|/cnt, so accumulate e1-e2 only
    float ao = tpos ? andp : 0.0f;
    float d1 = fmaxf(p1, ao) - 1.0f;
    float d2 = fmaxf(p2, ao) - 1.0f;
    float e12 = (d1 - d2) * (d1 + d2);
    #pragma unroll
    for (int j = 0; j < NUM_INST; ++j) {
        bool m = (k == j);
        s12[j] += m ? e12 : 0.0f;                          // v_cmp + cndmask + add
        cnt_s[j] += (unsigned)__popcll(__ballot(m));       // s_bcnt1 + s_add (scalar)
    }
}

__global__ __launch_bounds__(THREADS) void overlap_main_kernel(
    const float* __restrict__ preds, const float* __restrict__ conf,
    const int* __restrict__ inst, const float* __restrict__ overlap,
    float* __restrict__ ws)
{
    const int b   = blockIdx.y;
    const int tid = threadIdx.x;
    const int i0  = blockIdx.x * THREADS + tid;   // [0, 51200)
    const int i1  = i0 + HALF_VEC;

    const float4* p1v = (const float4*)(preds + (size_t)b * 2 * HWN);
    const float4* p2v = (const float4*)(preds + (size_t)b * 2 * HWN + HWN);
    const float4* cv  = (const float4*)(conf    + (size_t)b * HWN);
    const float4* tv  = (const float4*)(overlap + (size_t)b * HWN);
    const int4*   kv  = (const int4*)(inst      + (size_t)b * HWN);

    // Issue ALL 10 global loads before any use: 320 B/lane in flight.
    float4 A0 = p1v[i0]; float4 A1 = p1v[i1];
    float4 B0 = p2v[i0]; float4 B1 = p2v[i1];
    float4 C0 = cv[i0];  float4 C1 = cv[i1];
    float4 T0 = tv[i0];  float4 T1 = tv[i1];
    int4   K0 = kv[i0];  int4   K1 = kv[i1];

    float s12[NUM_INST];
    unsigned cnt_s[NUM_INST];
    #pragma unroll
    for (int j = 0; j < NUM_INST; ++j) { s12[j] = 0.0f; cnt_s[j] = 0u; }
    float accPos = 0.0f, accAll = 0.0f, accOr = 0.0f;
    unsigned posCnt = 0u;

    process_pixel(A0.x, B0.x, C0.x, T0.x, K0.x, s12, cnt_s, accPos, accAll, accOr, posCnt);
    process_pixel(A0.y, B0.y, C0.y, T0.y, K0.y, s12, cnt_s, accPos, accAll, accOr, posCnt);
    process_pixel(A0.z, B0.z, C0.z, T0.z, K0.z, s12, cnt_s, accPos, accAll, accOr, posCnt);
    process_pixel(A0.w, B0.w, C0.w, T0.w, K0.w, s12, cnt_s, accPos, accAll, accOr, posCnt);
    process_pixel(A1.x, B1.x, C1.x, T1.x, K1.x, s12, cnt_s, accPos, accAll, accOr, posCnt);
    process_pixel(A1.y, B1.y, C1.y, T1.y, K1.y, s12, cnt_s, accPos, accAll, accOr, posCnt);
    process_pixel(A1.z, B1.z, C1.z, T1.z, K1.z, s12, cnt_s, accPos, accAll, accOr, posCnt);
    process_pixel(A1.w, B1.w, C1.w, T1.w, K1.w, s12, cnt_s, accPos, accAll, accOr, posCnt);

    // Butterfly-reduce only the 19 per-lane float values (counts are wave-uniform SGPRs)
    float fv[19];
    #pragma unroll
    for (int j = 0; j < NUM_INST; ++j) fv[j] = s12[j];
    fv[16] = accPos; fv[17] = accAll; fv[18] = accOr;
    #pragma unroll
    for (int s = 32; s > 0; s >>= 1) {
        #pragma unroll
        for (int v = 0; v < 19; ++v) fv[v] += __shfl_xor(fv[v], s, 64);
    }

    __shared__ float wsum[4][NV];
    const int wave = tid >> 6;
    const int lane = tid & 63;
    if (lane == 0) {
        #pragma unroll
        for (int j = 0; j < NUM_INST; ++j) {
            wsum[wave][j]      = fv[j];
            wsum[wave][16 + j] = (float)cnt_s[j];
        }
        wsum[wave][32] = fv[16];
        wsum[wave][33] = fv[17];
        wsum[wave][34] = fv[18];
        wsum[wave][35] = (float)posCnt;
    }
    __syncthreads();
    if (tid < NV) {
        float s = wsum[0][tid] + wsum[1][tid] + wsum[2][tid] + wsum[3][tid];
        int g = blockIdx.y * NBLK + blockIdx.x;
        ws[tid * NBLK_TOT + g] = s;   // plain store, no atomics
    }
}

__global__ __launch_bounds__(576) void overlap_finalize_kernel(
    const float* __restrict__ ws, float* __restrict__ out)
{
    __shared__ float seg[BB][NV];
    __shared__ float perkey[BB][NUM_INST];
    __shared__ float pres[BB][NUM_INST];
    __shared__ float binst[BB];
    const int t = threadIdx.x;   // 576 = 2 * (8*36)

    {
        int row  = t >> 1;          // 0..287
        int half = t & 1;
        int b = row / NV, v = row - b * NV;
        const float4* p = (const float4*)(ws + v * NBLK_TOT + b * NBLK) + half * 25;
        float s = 0.0f;
        #pragma unroll
        for (int i = 0; i < 25; ++i) {
            float4 q = p[i];
            s += (q.x + q.y) + (q.z + q.w);
        }
        s += __shfl_xor(s, 1, 64);   // combine the two halves (adjacent lanes)
        if (half == 0) seg[b][v] = s;
    }
    __syncthreads();

    if (t < BB * NUM_INST) {
        int b = t >> 4, k = t & 15;
        float c = seg[b][16 + k];
        bool present = c > 0.0f;
        float sc = present ? c : 1.0f;
        perkey[b][k] = present ? (1.0f - fabsf(seg[b][k]) / sc) : 0.0f;
        pres[b][k]   = present ? 1.0f : 0.0f;
    }
    __syncthreads();

    if (t < BB) {
        float s = 0.0f, nk = 0.0f;
        for (int k = 0; k < NUM_INST; ++k) { s += perkey[t][k]; nk += pres[t][k]; }
        binst[t] = s / nk;
    }
    __syncthreads();

    if (t == 0) {
        float instLoss = 0.0f, posS = 0.0f, allS = 0.0f, orS = 0.0f, posC = 0.0f;
        for (int b = 0; b < BB; ++b) {
            instLoss += binst[b];
            posS += seg[b][32];
            allS += seg[b][33];
            orS  += seg[b][34];
            posC += seg[b][35];
        }
        instLoss *= (1.0f / (float)BB);
        const float N = (float)BB * (float)HWN;
        float negS = allS - posS;
        float andLoss = posS / posC + negS / (N - posC);
        float orLoss  = orS / N;
        out[0] = 0.5f * andLoss + 0.25f * orLoss + 0.25f * instLoss;
    }
}

extern "C" void kernel_launch(void* const* d_in, const int* in_sizes, int n_in,
                              void* d_out, int out_size, void* d_ws, size_t ws_size,
                              hipStream_t stream) {
    const float* preds   = (const float*)d_in[0];
    const float* conf    = (const float*)d_in[1];
    const int*   inst    = (const int*)d_in[2];
    const float* overlap = (const float*)d_in[3];
    // d_in[4] (inds) is unused by the reference computation.
    float* ws  = (float*)d_ws;
    float* out = (float*)d_out;

    dim3 grid(NBLK, BB);
    overlap_main_kernel<<<grid, THREADS, 0, stream>>>(preds, conf, inst, overlap, ws);
    overlap_finalize_kernel<<<1, 576, 0, stream>>>(ws, out);
}